// Round 6
// baseline (233.516 us; speedup 1.0000x reference)
//
#include <hip/hip_runtime.h>
#include <math.h>

typedef _Float16 half_t;
typedef __attribute__((ext_vector_type(8))) _Float16 half8;
typedef __attribute__((ext_vector_type(4))) _Float16 half4;
typedef __attribute__((ext_vector_type(2))) _Float16 half2v;
typedef __attribute__((ext_vector_type(4))) float floatx4;

#define BATCH   8
#define SEQ     4096
#define DM      512
#define NP      256
#define M_TOT   32768
#define NTOT    768
#define CHUNKS  256
#define CHUNK_LEN 16

__device__ __forceinline__ void async_load16(const void* g, void* l) {
    __builtin_amdgcn_global_load_lds((const __attribute__((address_space(1))) void*)g,
                                     (__attribute__((address_space(3))) void*)l,
                                     16, 0, 0);
}

// ---------------------------------------------------------------------------
// decay + x fp32->fp16 convert. 2 rows per wave.
// ---------------------------------------------------------------------------
__global__ __launch_bounds__(256) void decay_convert(const float* __restrict__ X,
                                                     const float* __restrict__ Wd,
                                                     const float* __restrict__ bd,
                                                     float* __restrict__ dec,
                                                     half_t* __restrict__ Xh) {
    const int wave = threadIdx.x >> 6;
    const int lane = threadIdx.x & 63;
    const int row0 = blockIdx.x * 8 + wave * 2;
    const float4* x0 = (const float4*)(X + (size_t)row0 * DM);
    const float4* x1 = x0 + 128;
    const float4* wd = (const float4*)Wd;
    float4 a0 = x0[2 * lane], a1 = x0[2 * lane + 1];
    float4 b0 = x1[2 * lane], b1 = x1[2 * lane + 1];
    float4 w0 = wd[2 * lane], w1 = wd[2 * lane + 1];
    float s0 = a0.x * w0.x + a0.y * w0.y + a0.z * w0.z + a0.w * w0.w
             + a1.x * w1.x + a1.y * w1.y + a1.z * w1.z + a1.w * w1.w;
    float s1 = b0.x * w0.x + b0.y * w0.y + b0.z * w0.z + b0.w * w0.w
             + b1.x * w1.x + b1.y * w1.y + b1.z * w1.z + b1.w * w1.w;
    half8 h0 = {(half_t)a0.x, (half_t)a0.y, (half_t)a0.z, (half_t)a0.w,
                (half_t)a1.x, (half_t)a1.y, (half_t)a1.z, (half_t)a1.w};
    half8 h1 = {(half_t)b0.x, (half_t)b0.y, (half_t)b0.z, (half_t)b0.w,
                (half_t)b1.x, (half_t)b1.y, (half_t)b1.z, (half_t)b1.w};
    *(half8*)(Xh + (size_t)row0 * DM + lane * 8) = h0;
    *(half8*)(Xh + (size_t)(row0 + 1) * DM + lane * 8) = h1;
#pragma unroll
    for (int off = 32; off > 0; off >>= 1) {
        s0 += __shfl_down(s0, off, 64);
        s1 += __shfl_down(s1, off, 64);
    }
    if (lane == 0) {
        dec[row0]     = 1.0f / (1.0f + __expf(-(s0 + bd[0])));
        dec[row0 + 1] = 1.0f / (1.0f + __expf(-(s1 + bd[0])));
    }
}

// ---------------------------------------------------------------------------
// Wcat_t[768][512] fp16 = [Wi^T ; Wa^T], LDS-tiled 64x64 so both the global
// read (over n) and the global write (over k) are coalesced.
// ---------------------------------------------------------------------------
__global__ __launch_bounds__(256) void wcat_transpose(const float* __restrict__ Wi,
                                                      const float* __restrict__ Wa,
                                                      half_t* __restrict__ Wt) {
    __shared__ float tile[64][65];
    const int bn_ = blockIdx.x >> 3;          // 0..11  (n tile)
    const int bk_ = blockIdx.x & 7;           // 0..7   (k tile)
    const int n0 = bn_ * 64, k0 = bk_ * 64;
    const int c = threadIdx.x & 63;
    const int r = threadIdx.x >> 6;           // 0..3
    const bool from_wi = (n0 < DM);
    const float* src = from_wi ? Wi : Wa;
    const int ncols   = from_wi ? DM : NP;
    const int ncol0   = from_wi ? n0 : (n0 - DM);
#pragma unroll
    for (int i = 0; i < 16; ++i) {
        const int rr = r + i * 4;             // k within tile
        tile[rr][c] = src[(size_t)(k0 + rr) * ncols + ncol0 + c];
    }
    __syncthreads();
#pragma unroll
    for (int i = 0; i < 16; ++i) {
        const int rr = r + i * 4;             // n within tile
        Wt[(size_t)(n0 + rr) * DM + k0 + c] = (half_t)tile[c][rr];
    }
}

// ---------------------------------------------------------------------------
// Fused MFMA GEMM (proven R3 structure, BK=32, 16 KB LDS). Epilogue now
// writes inj as fp16 (halves write traffic); out is written only by scan_final.
// ---------------------------------------------------------------------------
__global__ __launch_bounds__(256) void gemm_fused(const half_t* __restrict__ Xh,
                                                  const half_t* __restrict__ Wt,
                                                  const float* __restrict__ bi,
                                                  const float* __restrict__ ba,
                                                  half_t* __restrict__ injh,
                                                  half_t* __restrict__ angles) {
    __shared__ __align__(16) char As[8192];
    __shared__ __align__(16) char Bs[8192];

    const int bm   = blockIdx.x;
    const int bn   = blockIdx.y;
    const int tid  = threadIdx.x;
    const int wave = tid >> 6;
    const int lane = tid & 63;
    const int quad = lane >> 4;
    const int l16  = lane & 15;
    const int wrow = wave >> 1;
    const int wcol = wave & 1;

    floatx4 acc[4][4];
#pragma unroll
    for (int i = 0; i < 4; ++i)
#pragma unroll
        for (int j = 0; j < 4; ++j) acc[i][j] = (floatx4){0.f, 0.f, 0.f, 0.f};

    const int s0 = wave * 128 + lane;
    const int s1 = s0 + 64;
    const int r0 = s0 >> 2, kql0 = (s0 & 3) ^ ((r0 >> 1) & 3);
    const int r1 = s1 >> 2, kql1 = (s1 & 3) ^ ((r1 >> 1) & 3);
    const half_t* gA0 = Xh + (size_t)(bm * 128 + r0) * DM + kql0 * 8;
    const half_t* gA1 = Xh + (size_t)(bm * 128 + r1) * DM + kql1 * 8;
    const half_t* gB0 = Wt + (size_t)(bn * 128 + r0) * DM + kql0 * 8;
    const half_t* gB1 = Wt + (size_t)(bn * 128 + r1) * DM + kql1 * 8;
    char* lA0 = As + wave * 2048;
    char* lA1 = As + wave * 2048 + 1024;
    char* lB0 = Bs + wave * 2048;
    char* lB1 = Bs + wave * 2048 + 1024;

    for (int k0 = 0; k0 < DM; k0 += 32) {
        async_load16(gA0 + k0, lA0);
        async_load16(gA1 + k0, lA1);
        async_load16(gB0 + k0, lB0);
        async_load16(gB1 + k0, lB1);
        __syncthreads();

        half8 af[4], bf[4];
#pragma unroll
        for (int mt = 0; mt < 4; ++mt) {
            const int r = wrow * 64 + mt * 16 + l16;
            af[mt] = *(const half8*)(As + r * 64 + ((quad ^ ((r >> 1) & 3)) << 4));
        }
#pragma unroll
        for (int nt = 0; nt < 4; ++nt) {
            const int r = wcol * 64 + nt * 16 + l16;
            bf[nt] = *(const half8*)(Bs + r * 64 + ((quad ^ ((r >> 1) & 3)) << 4));
        }
#pragma unroll
        for (int mt = 0; mt < 4; ++mt)
#pragma unroll
            for (int nt = 0; nt < 4; ++nt)
                acc[mt][nt] = __builtin_amdgcn_mfma_f32_16x16x32_f16(af[mt], bf[nt],
                                                                     acc[mt][nt], 0, 0, 0);
        __syncthreads();
    }

    const int colbase = bn * 128 + wcol * 64;
#pragma unroll
    for (int nt = 0; nt < 4; ++nt) {
        const int col = colbase + nt * 16 + l16;
        const bool is_inj = col < DM;
        const float bias = is_inj ? bi[col] : ba[col - DM];
#pragma unroll
        for (int mt = 0; mt < 4; ++mt) {
            const int rowb = bm * 128 + wrow * 64 + mt * 16 + quad * 4;
#pragma unroll
            for (int r = 0; r < 4; ++r) {
                const float v = acc[mt][nt][r] + bias;
                const int row = rowb + r;
                if (is_inj) injh[(size_t)row * DM + col] = (half_t)v;
                else        angles[(size_t)row * NP + (col - DM)] = (half_t)v;
            }
        }
    }
}

// ---------------------------------------------------------------------------
// sum1: per-chunk summaries (no state writes). LEN=16, 2 chunks/block,
// 2 pairs/thread, simple loop (TLP over ILP).
// ---------------------------------------------------------------------------
__global__ __launch_bounds__(256) void scan_sum1(const half_t* __restrict__ angles,
                                                 const float* __restrict__ decays,
                                                 const half_t* __restrict__ injh,
                                                 float* __restrict__ thetaC,
                                                 float2* __restrict__ hend,
                                                 float* __restrict__ Dprod) {
    const int b   = blockIdx.x >> 7;
    const int sub = threadIdx.x >> 7;
    const int th  = threadIdx.x & 127;
    const int c   = (blockIdx.x & 127) * 2 + sub;
    const int p0  = th * 2;
    const int t0  = c * CHUNK_LEN;

    const half_t* ap = angles + (size_t)(b * SEQ + t0) * NP + p0;
    const half_t* ip = injh + (size_t)(b * SEQ + t0) * DM + 2 * p0;
    const float*  dp = decays + b * SEQ + t0;

    float h0a = 0, h1a = 0, h0b = 0, h1b = 0, tha = 0, thb = 0, dc = 1.0f;
#pragma unroll 4
    for (int i = 0; i < CHUNK_LEN; ++i) {
        half2v av = *(const half2v*)(ap + (size_t)i * NP);
        half4  uv = *(const half4*)(ip + (size_t)i * DM);
        float d = dp[i];
        float a0 = (float)av[0], a1 = (float)av[1];
        float s0, c0, s1, c1;
        __sincosf(a0, &s0, &c0);
        __sincosf(a1, &s1, &c1);
        float n0a = fmaf(d, c0 * h0a - s0 * h1a, (float)uv[0]);
        float n1a = fmaf(d, s0 * h0a + c0 * h1a, (float)uv[1]);
        float n0b = fmaf(d, c1 * h0b - s1 * h1b, (float)uv[2]);
        float n1b = fmaf(d, s1 * h0b + c1 * h1b, (float)uv[3]);
        h0a = n0a; h1a = n1a; h0b = n0b; h1b = n1b;
        tha += a0; thb += a1; dc *= d;
    }
    const size_t cbase = (size_t)(b * CHUNKS + c) * NP + p0;
    *(float2*)(thetaC + cbase) = make_float2(tha, thb);
    hend[cbase]     = make_float2(h0a, h1a);
    hend[cbase + 1] = make_float2(h0b, h1b);
    if (th == 0) Dprod[b * CHUNKS + c] = dc;
}

// ---------------------------------------------------------------------------
// chunk-operator scan: 32 blocks x 64 threads (1 pair/thread) so the ~10 MB
// of summary traffic spreads over 32 CUs instead of 8.
// ---------------------------------------------------------------------------
__global__ __launch_bounds__(64) void scan_chunks(const float* __restrict__ thetaC,
                                                  const float2* __restrict__ hend,
                                                  const float* __restrict__ Dprod,
                                                  float2* __restrict__ hentry) {
    const int b = blockIdx.x >> 2;
    const int p = (blockIdx.x & 3) * 64 + threadIdx.x;
    const float* Dp = Dprod + b * CHUNKS;
    float h0 = 0, h1 = 0;
#pragma unroll 4
    for (int c = 0; c < CHUNKS; ++c) {
        const size_t idx = (size_t)(b * CHUNKS + c) * NP + p;
        hentry[idx] = make_float2(h0, h1);
        float th = thetaC[idx];
        float D  = Dp[c];
        float2 he = hend[idx];
        float s, cc;
        __sincosf(th, &s, &cc);
        float n0 = fmaf(D, cc * h0 - s * h1, he.x);
        float n1 = fmaf(D, s * h0 + cc * h1, he.y);
        h0 = n0;
        h1 = n1;
    }
}

// ---------------------------------------------------------------------------
// final: redo local scan seeded with chunk entry state; write out (only
// writer of d_out).
// ---------------------------------------------------------------------------
__global__ __launch_bounds__(256) void scan_final(const half_t* __restrict__ angles,
                                                  const float* __restrict__ decays,
                                                  const half_t* __restrict__ injh,
                                                  const float2* __restrict__ hentry,
                                                  float* __restrict__ out) {
    const int b   = blockIdx.x >> 7;
    const int sub = threadIdx.x >> 7;
    const int th  = threadIdx.x & 127;
    const int c   = (blockIdx.x & 127) * 2 + sub;
    const int p0  = th * 2;
    const int t0  = c * CHUNK_LEN;

    const half_t* ap = angles + (size_t)(b * SEQ + t0) * NP + p0;
    const half_t* ip = injh + (size_t)(b * SEQ + t0) * DM + 2 * p0;
    const float*  dp = decays + b * SEQ + t0;
    float*        op = out + (size_t)(b * SEQ + t0) * DM + 2 * p0;

    const size_t ebase = (size_t)(b * CHUNKS + c) * NP + p0;
    float2 ea = hentry[ebase];
    float2 eb = hentry[ebase + 1];
    float h0a = ea.x, h1a = ea.y, h0b = eb.x, h1b = eb.y;

#pragma unroll 4
    for (int i = 0; i < CHUNK_LEN; ++i) {
        half2v av = *(const half2v*)(ap + (size_t)i * NP);
        half4  uv = *(const half4*)(ip + (size_t)i * DM);
        float d = dp[i];
        float a0 = (float)av[0], a1 = (float)av[1];
        float s0, c0, s1, c1;
        __sincosf(a0, &s0, &c0);
        __sincosf(a1, &s1, &c1);
        float n0a = fmaf(d, c0 * h0a - s0 * h1a, (float)uv[0]);
        float n1a = fmaf(d, s0 * h0a + c0 * h1a, (float)uv[1]);
        float n0b = fmaf(d, c1 * h0b - s1 * h1b, (float)uv[2]);
        float n1b = fmaf(d, s1 * h0b + c1 * h1b, (float)uv[3]);
        h0a = n0a; h1a = n1a; h0b = n0b; h1b = n1b;
        *(float4*)(op + (size_t)i * DM) = make_float4(h0a, h1a, h0b, h1b);
    }
}

// ---------------------------------------------------------------------------
extern "C" void kernel_launch(void* const* d_in, const int* in_sizes, int n_in,
                              void* d_out, int out_size, void* d_ws, size_t ws_size,
                              hipStream_t stream) {
    const float* x  = (const float*)d_in[0];
    const float* Wa = (const float*)d_in[1];
    const float* ba = (const float*)d_in[2];
    const float* Wd = (const float*)d_in[3];
    const float* bd = (const float*)d_in[4];
    const float* Wi = (const float*)d_in[5];
    const float* bi = (const float*)d_in[6];
    float* out = (float*)d_out;

    char* ws = (char*)d_ws;
    // x_h dead after gemm_fused; scan summaries overlay it.
    half_t* x_h     = (half_t*)(ws);                  // 33,554,432 B @ 0
    float*  thetaC  = (float*)(ws);                   //  2,097,152 B (overlay)
    float2* hend    = (float2*)(ws + 2097152);        //  4,194,304 B (overlay)
    float*  Dprod   = (float*)(ws + 6291456);         //      8,192 B (overlay)
    float2* hentry  = (float2*)(ws + 6299648);        //  4,194,304 B (overlay)
    half_t* angles  = (half_t*)(ws + 33554432);       // 16,777,216 B [B,T,P] fp16
    half_t* injh    = (half_t*)(ws + 50331648);       // 33,554,432 B [B,T,D] fp16
    float*  decays  = (float*)(ws + 83886080);        //    131,072 B [B,T]
    half_t* Wcat_t  = (half_t*)(ws + 84017152);       //    786,432 B [768][512] fp16
    // total: 84,803,584 B

    decay_convert<<<M_TOT / 8, 256, 0, stream>>>(x, Wd, bd, decays, x_h);
    wcat_transpose<<<96, 256, 0, stream>>>(Wi, Wa, Wcat_t);
    gemm_fused<<<dim3(M_TOT / 128, NTOT / 128), 256, 0, stream>>>(x_h, Wcat_t, bi, ba, injh, angles);

    scan_sum1<<<BATCH * CHUNKS / 2, 256, 0, stream>>>(angles, decays, injh, thetaC, hend, Dprod);
    scan_chunks<<<32, 64, 0, stream>>>(thetaC, hend, Dprod, hentry);
    scan_final<<<BATCH * CHUNKS / 2, 256, 0, stream>>>(angles, decays, injh, hentry, out);
}